// Round 1
// baseline (702.275 us; speedup 1.0000x reference)
//
#include <hip/hip_runtime.h>
#include <math.h>

#define LL 2304
#define HH 48
#define WW 48
#define BB 2
#define CI 96
#define DM 192
#define DI 384
#define KK 4
#define RR 12
#define NN 16
#define KC 44
#define CH 64
#define LEN 36   // CH*LEN == LL

__device__ __forceinline__ float gelu_f(float x){
    return 0.5f*x*(1.0f+erff(x*0.70710678118654752f));
}
__device__ __forceinline__ float silu_f(float x){
    return x/(1.0f+__expf(-x));
}
__device__ __forceinline__ float softplus_f(float x){
    return fmaxf(x,0.0f) + log1pf(__expf(-fabsf(x)));
}

// ---------- pattern-P GEMM kernels: channel-major act (b,C,L), 16-out register block ----------

__global__ __launch_bounds__(256) void k_init(const float* __restrict__ x, const float* __restrict__ w,
        const float* __restrict__ bias, float* __restrict__ x1){
    int l = blockIdx.x*256 + threadIdx.x;
    int o0 = blockIdx.y*16;
    int b = blockIdx.z;
    const float* xb = x + (size_t)b*CI*LL + l;
    float acc[16];
    #pragma unroll
    for(int j=0;j<16;j++) acc[j] = bias[o0+j];
    for(int c=0;c<CI;c++){
        float xv = xb[c*LL];
        #pragma unroll
        for(int j=0;j<16;j++) acc[j] += w[(o0+j)*CI + c]*xv;
    }
    float* ob = x1 + (size_t)b*DM*LL + o0*LL + l;
    #pragma unroll
    for(int j=0;j<16;j++) ob[j*LL] = gelu_f(acc[j]);
}

__global__ __launch_bounds__(256) void k_inproj(const float* __restrict__ x1, const float* __restrict__ w,
        float* __restrict__ xx, float* __restrict__ z){
    int l = blockIdx.x*256 + threadIdx.x;
    int o0 = blockIdx.y*16; int b = blockIdx.z;
    const float* xb = x1 + (size_t)b*DM*LL + l;
    float acc[16];
    #pragma unroll
    for(int j=0;j<16;j++) acc[j] = 0.f;
    for(int c=0;c<DM;c++){
        float xv = xb[c*LL];
        #pragma unroll
        for(int j=0;j<16;j++) acc[j] += w[(o0+j)*DM + c]*xv;
    }
    float* ob = (o0 < DI) ? (xx + (size_t)b*DI*LL + o0*LL + l)
                          : (z  + (size_t)b*DI*LL + (o0-DI)*LL + l);
    #pragma unroll
    for(int j=0;j<16;j++) ob[j*LL] = acc[j];
}

__global__ __launch_bounds__(256) void k_dwconv(const float* __restrict__ xx, const float* __restrict__ cw,
        const float* __restrict__ cb, float* __restrict__ xc){
    int l = blockIdx.x*256 + threadIdx.x;
    int d = blockIdx.y; int b = blockIdx.z;
    int h = l/WW, w = l%WW;
    const float* src = xx + ((size_t)b*DI + d)*LL;
    float acc = cb[d];
    #pragma unroll
    for(int dh=-1;dh<=1;dh++){
        int hh = h+dh; if(hh<0||hh>=HH) continue;
        #pragma unroll
        for(int dw=-1;dw<=1;dw++){
            int w2 = w+dw; if(w2<0||w2>=WW) continue;
            acc += cw[d*9 + (dh+1)*3 + (dw+1)] * src[hh*WW + w2];
        }
    }
    xc[((size_t)b*DI + d)*LL + l] = silu_f(acc);
}

__global__ __launch_bounds__(256) void k_proj(const float* __restrict__ xc, const float* __restrict__ w,
        float* __restrict__ pj){
    int l = blockIdx.x*256 + threadIdx.x;
    int o0 = blockIdx.y*16; int b = blockIdx.z;
    const float* xb = xc + (size_t)b*DI*LL + l;
    float acc[16];
    #pragma unroll
    for(int j=0;j<16;j++) acc[j] = 0.f;
    for(int c=0;c<DI;c++){
        float xv = xb[c*LL];
        #pragma unroll
        for(int j=0;j<16;j++) acc[j] += w[(o0+j)*DI + c]*xv;
    }
    float* ob = pj + ((size_t)b*(KK*KC) + o0)*LL + l;
    #pragma unroll
    for(int j=0;j<16;j++) ob[j*LL] = acc[j];
}

// ---------- transpose (b,C,L) -> (b,L,C) for xc and z ----------
__global__ __launch_bounds__(256) void k_transpose(const float* __restrict__ xc, const float* __restrict__ z,
        float* __restrict__ xcT, float* __restrict__ zT){
    __shared__ float tile[32][33];
    int which = blockIdx.z >> 1;
    int b = blockIdx.z & 1;
    const float* src = which ? z : xc;
    float* dst = which ? zT : xcT;
    int l0 = blockIdx.x*32, d0 = blockIdx.y*32;
    int tx = threadIdx.x & 31, ty = threadIdx.x >> 5;
    #pragma unroll
    for(int j=0;j<4;j++)
        tile[ty+8*j][tx] = src[((size_t)b*DI + d0+ty+8*j)*LL + l0+tx];
    __syncthreads();
    #pragma unroll
    for(int j=0;j<4;j++)
        dst[((size_t)b*LL + l0+ty+8*j)*DI + d0+tx] = tile[tx][ty+8*j];
}

// ---------- chunked selective scan ----------
__device__ __forceinline__ int perm_pos(int k, int l){
    int lk = (k>=2) ? (LL-1-l) : l;
    return (k&1) ? ((lk%WW)*WW + lk/WW) : lk;
}

__global__ __launch_bounds__(64) void k_scan1(const float* __restrict__ xcT, const float* __restrict__ pj,
        const float* __restrict__ dtw, const float* __restrict__ dtb, const float* __restrict__ alogs,
        float* __restrict__ gbuf, float* __restrict__ Sbuf){
    int chunk = blockIdx.x;
    int d = blockIdx.y*64 + threadIdx.x;
    int bk = blockIdx.z; int b = bk>>2, k = bk&3;
    float wr[RR];
    #pragma unroll
    for(int r=0;r<RR;r++) wr[r] = dtw[((size_t)k*DI + d)*RR + r];
    float dtbv = dtb[k*DI + d];
    float a[NN], h[NN];
    #pragma unroll
    for(int n=0;n<NN;n++){ a[n] = -__expf(alogs[((size_t)k*DI + d)*NN + n]); h[n]=0.f; }
    float S = 0.f;
    const float* pjb = pj + ((size_t)b*(KK*KC) + k*KC)*LL;
    for(int s=0;s<LEN;s++){
        int l = chunk*LEN + s;
        int p = perm_pos(k, l);
        float u = xcT[((size_t)b*LL + p)*DI + d];
        float draw = dtbv;
        #pragma unroll
        for(int r=0;r<RR;r++) draw += wr[r]*pjb[r*LL + p];
        float dt = softplus_f(draw);
        S += dt;
        float du = dt*u;
        #pragma unroll
        for(int n=0;n<NN;n++){
            float Bv = pjb[(RR+n)*LL + p];
            h[n] = __expf(dt*a[n])*h[n] + du*Bv;
        }
    }
    int base = (bk*CH + chunk)*NN;
    #pragma unroll
    for(int n=0;n<NN;n++) gbuf[(size_t)(base+n)*DI + d] = h[n];
    Sbuf[(size_t)(bk*CH + chunk)*DI + d] = S;
}

__global__ __launch_bounds__(256) void k_scan2(const float* __restrict__ alogs, const float* __restrict__ Sbuf,
        float* __restrict__ gbuf){
    int id = blockIdx.x*256 + threadIdx.x;
    int d = id % DI;
    int n = (id/DI) % NN;
    int bk = id/(DI*NN);
    int k = bk & 3;
    float a = -__expf(alogs[((size_t)k*DI + d)*NN + n]);
    float h = 0.f;
    for(int j=0;j<CH;j++){
        float S = Sbuf[(size_t)(bk*CH + j)*DI + d];
        size_t gi = (size_t)((bk*CH + j)*NN + n)*DI + d;
        float g = gbuf[gi];
        gbuf[gi] = h;                 // store h0 for chunk j in place
        h = __expf(a*S)*h + g;
    }
}

__global__ __launch_bounds__(64) void k_scan3(const float* __restrict__ xcT, const float* __restrict__ pj,
        const float* __restrict__ dtw, const float* __restrict__ dtb, const float* __restrict__ alogs,
        const float* __restrict__ gbuf, float* __restrict__ yout){
    int chunk = blockIdx.x;
    int d = blockIdx.y*64 + threadIdx.x;
    int bk = blockIdx.z; int b = bk>>2, k = bk&3;
    float wr[RR];
    #pragma unroll
    for(int r=0;r<RR;r++) wr[r] = dtw[((size_t)k*DI + d)*RR + r];
    float dtbv = dtb[k*DI + d];
    float a[NN], h[NN];
    int base = (bk*CH + chunk)*NN;
    #pragma unroll
    for(int n=0;n<NN;n++){
        a[n] = -__expf(alogs[((size_t)k*DI + d)*NN + n]);
        h[n] = gbuf[(size_t)(base+n)*DI + d];
    }
    const float* pjb = pj + ((size_t)b*(KK*KC) + k*KC)*LL;
    for(int s=0;s<LEN;s++){
        int l = chunk*LEN + s;
        int p = perm_pos(k, l);
        float u = xcT[((size_t)b*LL + p)*DI + d];
        float draw = dtbv;
        #pragma unroll
        for(int r=0;r<RR;r++) draw += wr[r]*pjb[r*LL + p];
        float dt = softplus_f(draw);
        float du = dt*u;
        float y = 0.f;
        #pragma unroll
        for(int n=0;n<NN;n++){
            float Bv = pjb[(RR+n)*LL + p];
            float Cv = pjb[(RR+NN+n)*LL + p];
            h[n] = __expf(dt*a[n])*h[n] + du*Bv;
            y += h[n]*Cv;
        }
        yout[((size_t)bk*LL + p)*DI + d] = y;
    }
}

// ---------- merge: sum 4 dirs + D-term, LayerNorm, silu(z) gate, transpose to (b,C,L) ----------
__global__ __launch_bounds__(256) void k_merge(const float* __restrict__ yout, const float* __restrict__ xcT,
        const float* __restrict__ zT, const float* __restrict__ Ds,
        const float* __restrict__ lng, const float* __restrict__ lnb,
        float* __restrict__ ygT){
    __shared__ float tile[32*385];
    int p0 = blockIdx.x*32; int b = blockIdx.y;
    for(int idx=threadIdx.x; idx<32*DI; idx+=256){
        int pp = idx/DI, d = idx%DI; int p = p0+pp;
        float dsum = Ds[d] + Ds[DI+d] + Ds[2*DI+d] + Ds[3*DI+d];
        float v = dsum * xcT[((size_t)b*LL + p)*DI + d];
        #pragma unroll
        for(int kk=0;kk<4;kk++) v += yout[((size_t)(b*4+kk)*LL + p)*DI + d];
        tile[pp*385 + d] = v;
    }
    __syncthreads();
    int lane = threadIdx.x & 63, wv = threadIdx.x >> 6;
    for(int i=0;i<8;i++){
        int pp = wv*8 + i; int p = p0+pp;
        float s1=0.f, s2=0.f;
        float vals[6];
        #pragma unroll
        for(int j=0;j<6;j++){ float v = tile[pp*385 + lane + 64*j]; vals[j]=v; s1+=v; s2+=v*v; }
        #pragma unroll
        for(int m=1;m<64;m<<=1){ s1 += __shfl_xor(s1,m); s2 += __shfl_xor(s2,m); }
        float mu = s1*(1.0f/DI);
        float var = s2*(1.0f/DI) - mu*mu;
        float rstd = rsqrtf(var + 1e-5f);
        #pragma unroll
        for(int j=0;j<6;j++){
            int c = lane + 64*j;
            float zv = zT[((size_t)b*LL + p)*DI + c];
            float y = (vals[j]-mu)*rstd*lng[c] + lnb[c];
            tile[pp*385 + c] = y * silu_f(zv);
        }
    }
    __syncthreads();
    for(int idx=threadIdx.x; idx<32*DI; idx+=256){
        int pp = idx & 31, d = idx >> 5;
        ygT[((size_t)b*DI + d)*LL + p0 + pp] = tile[pp*385 + d];
    }
}

__global__ __launch_bounds__(256) void k_outproj(const float* __restrict__ ygT, const float* __restrict__ w,
        float* __restrict__ yo){
    int l = blockIdx.x*256 + threadIdx.x;
    int o0 = blockIdx.y*16; int b = blockIdx.z;
    const float* xb = ygT + (size_t)b*DI*LL + l;
    float acc[16];
    #pragma unroll
    for(int j=0;j<16;j++) acc[j] = 0.f;
    for(int c=0;c<DI;c++){
        float xv = xb[c*LL];
        #pragma unroll
        for(int j=0;j<16;j++) acc[j] += w[(o0+j)*DI + c]*xv;
    }
    float* ob = yo + (size_t)b*DM*LL + o0*LL + l;
    #pragma unroll
    for(int j=0;j<16;j++) ob[j*LL] = acc[j];
}

__global__ __launch_bounds__(256) void k_final(const float* __restrict__ yo, const float* __restrict__ x1,
        const float* __restrict__ w, const float* __restrict__ bias, float* __restrict__ out){
    int l = blockIdx.x*256 + threadIdx.x;
    int o0 = blockIdx.y*16; int b = blockIdx.z;
    const float* yb = yo + (size_t)b*DM*LL + l;
    const float* rb = x1 + (size_t)b*DM*LL + l;
    float acc[16];
    #pragma unroll
    for(int j=0;j<16;j++) acc[j] = bias[o0+j];
    for(int c=0;c<DM;c++){
        float xv = yb[c*LL] + rb[c*LL];
        #pragma unroll
        for(int j=0;j<16;j++) acc[j] += w[(o0+j)*DM + c]*xv;
    }
    float* ob = out + (size_t)b*CI*LL + o0*LL + l;
    #pragma unroll
    for(int j=0;j<16;j++) ob[j*LL] = gelu_f(acc[j]);
}

extern "C" void kernel_launch(void* const* d_in, const int* in_sizes, int n_in,
                              void* d_out, int out_size, void* d_ws, size_t ws_size,
                              hipStream_t stream) {
    const float* x        = (const float*)d_in[0];
    const float* w_init   = (const float*)d_in[1];
    const float* b_init   = (const float*)d_in[2];
    const float* w_fina   = (const float*)d_in[3];
    const float* b_fina   = (const float*)d_in[4];
    const float* in_proj_w= (const float*)d_in[5];
    const float* conv_w   = (const float*)d_in[6];
    const float* conv_b   = (const float*)d_in[7];
    const float* x_proj_w = (const float*)d_in[8];
    const float* dt_w     = (const float*)d_in[9];
    const float* dt_b     = (const float*)d_in[10];
    const float* A_logs   = (const float*)d_in[11];
    const float* Ds       = (const float*)d_in[12];
    const float* ln_g     = (const float*)d_in[13];
    const float* ln_b     = (const float*)d_in[14];
    const float* out_proj_w=(const float*)d_in[15];

    float* ws = (float*)d_ws;
    float* x1   = ws;                      // 884736
    float* xx   = x1 + 884736;             // 1769472 (reused as ygT)
    float* z    = xx + 1769472;            // 1769472 (reused as yo)
    float* xc   = z  + 1769472;            // 1769472
    float* xcT  = xc + 1769472;            // 1769472
    float* zT   = xcT+ 1769472;            // 1769472
    float* pj   = zT + 1769472;            // 811008
    float* gbuf = pj + 811008;             // 3145728
    float* Sbuf = gbuf + 3145728;          // 196608
    float* yout = Sbuf + 196608;           // 7077888
    // total 20,963,328 floats = 83.9 MB

    dim3 blk(256);
    k_init   <<<dim3(9,12,BB), blk, 0, stream>>>(x, w_init, b_init, x1);
    k_inproj <<<dim3(9,48,BB), blk, 0, stream>>>(x1, in_proj_w, xx, z);
    k_dwconv <<<dim3(9,DI,BB), blk, 0, stream>>>(xx, conv_w, conv_b, xc);
    k_proj   <<<dim3(9,11,BB), blk, 0, stream>>>(xc, x_proj_w, pj);
    k_transpose<<<dim3(72,12,2*BB), blk, 0, stream>>>(xc, z, xcT, zT);
    k_scan1  <<<dim3(CH,6,BB*KK), dim3(64), 0, stream>>>(xcT, pj, dt_w, dt_b, A_logs, gbuf, Sbuf);
    k_scan2  <<<dim3(192), blk, 0, stream>>>(A_logs, Sbuf, gbuf);
    k_scan3  <<<dim3(CH,6,BB*KK), dim3(64), 0, stream>>>(xcT, pj, dt_w, dt_b, A_logs, gbuf, yout);
    k_merge  <<<dim3(72,BB), blk, 0, stream>>>(yout, xcT, zT, Ds, ln_g, ln_b, xx);
    k_outproj<<<dim3(9,12,BB), blk, 0, stream>>>(xx, out_proj_w, z);
    k_final  <<<dim3(9,6,BB), blk, 0, stream>>>(z, x1, w_fina, b_fina, (float*)d_out);
}

// Round 2
// 514.612 us; speedup vs baseline: 1.3647x; 1.3647x over previous
//
#include <hip/hip_runtime.h>
#include <math.h>

#define LL 2304
#define HH 48
#define WW 48
#define BB 2
#define CI 96
#define DM 192
#define DI 384
#define KK 4
#define RR 12
#define NN 16
#define KC 44
#define CH 96
#define LEN 24   // CH*LEN == LL

__device__ __forceinline__ float gelu_f(float x){
    return 0.5f*x*(1.0f+erff(x*0.70710678118654752f));
}
__device__ __forceinline__ float silu_f(float x){
    return x/(1.0f+__expf(-x));
}
__device__ __forceinline__ float softplus_f(float x){
    return fmaxf(x,0.0f) + log1pf(__expf(-fabsf(x)));
}

// ---------- GEMM pattern: 256 l-lanes x 16 outputs, weights staged in LDS ----------
template<int C>
__device__ __forceinline__ void gemm16_acc(const float* __restrict__ xb, const float* __restrict__ w,
        int o0, float* wl, float acc[16], int tid){
    // stage rows o0..o0+15 of w (each C contiguous floats) into LDS
    for(int idx=tid; idx<16*C; idx+=256) wl[idx] = w[(size_t)o0*C + idx];
    __syncthreads();
    #pragma unroll 2
    for(int c=0;c<C;c+=4){
        float x0=xb[(size_t)(c+0)*LL], x1=xb[(size_t)(c+1)*LL];
        float x2=xb[(size_t)(c+2)*LL], x3=xb[(size_t)(c+3)*LL];
        #pragma unroll
        for(int o=0;o<16;o++){
            float4 wq = *reinterpret_cast<const float4*>(wl + o*C + c);
            acc[o] = fmaf(wq.x,x0, fmaf(wq.y,x1, fmaf(wq.z,x2, fmaf(wq.w,x3, acc[o]))));
        }
    }
}

__global__ __launch_bounds__(256) void k_init(const float* __restrict__ x, const float* __restrict__ w,
        const float* __restrict__ bias, float* __restrict__ x1){
    __shared__ float wl[16*CI];
    int l = blockIdx.x*256 + threadIdx.x;
    int o0 = blockIdx.y*16; int b = blockIdx.z;
    float acc[16];
    #pragma unroll
    for(int j=0;j<16;j++) acc[j] = bias[o0+j];
    gemm16_acc<CI>(x + (size_t)b*CI*LL + l, w, o0, wl, acc, threadIdx.x);
    float* ob = x1 + (size_t)b*DM*LL + o0*LL + l;
    #pragma unroll
    for(int j=0;j<16;j++) ob[j*LL] = gelu_f(acc[j]);
}

__global__ __launch_bounds__(256) void k_inproj(const float* __restrict__ x1, const float* __restrict__ w,
        float* __restrict__ xx, float* __restrict__ z){
    __shared__ float wl[16*DM];
    int l = blockIdx.x*256 + threadIdx.x;
    int o0 = blockIdx.y*16; int b = blockIdx.z;
    float acc[16];
    #pragma unroll
    for(int j=0;j<16;j++) acc[j] = 0.f;
    gemm16_acc<DM>(x1 + (size_t)b*DM*LL + l, w, o0, wl, acc, threadIdx.x);
    float* ob = (o0 < DI) ? (xx + (size_t)b*DI*LL + o0*LL + l)
                          : (z  + (size_t)b*DI*LL + (o0-DI)*LL + l);
    #pragma unroll
    for(int j=0;j<16;j++) ob[j*LL] = acc[j];
}

__global__ __launch_bounds__(256) void k_dwconv(const float* __restrict__ xx, const float* __restrict__ cw,
        const float* __restrict__ cb, float* __restrict__ xc){
    int l = blockIdx.x*256 + threadIdx.x;
    int d = blockIdx.y; int b = blockIdx.z;
    int h = l/WW, w = l%WW;
    const float* src = xx + ((size_t)b*DI + d)*LL;
    float acc = cb[d];
    #pragma unroll
    for(int dh=-1;dh<=1;dh++){
        int hh = h+dh; if(hh<0||hh>=HH) continue;
        #pragma unroll
        for(int dw=-1;dw<=1;dw++){
            int w2 = w+dw; if(w2<0||w2>=WW) continue;
            acc += cw[d*9 + (dh+1)*3 + (dw+1)] * src[hh*WW + w2];
        }
    }
    xc[((size_t)b*DI + d)*LL + l] = silu_f(acc);
}

__global__ __launch_bounds__(256) void k_proj(const float* __restrict__ xc, const float* __restrict__ w,
        float* __restrict__ pj){
    __shared__ float wl[16*DI];
    int l = blockIdx.x*256 + threadIdx.x;
    int o0 = blockIdx.y*16; int b = blockIdx.z;
    float acc[16];
    #pragma unroll
    for(int j=0;j<16;j++) acc[j] = 0.f;
    gemm16_acc<DI>(xc + (size_t)b*DI*LL + l, w, o0, wl, acc, threadIdx.x);
    float* ob = pj + ((size_t)b*(KK*KC) + o0)*LL + l;
    #pragma unroll
    for(int j=0;j<16;j++) ob[j*LL] = acc[j];
}

// ---------- transpose (b,C,L) -> (b,L,C) for xc and z ----------
__global__ __launch_bounds__(256) void k_transpose(const float* __restrict__ xc, const float* __restrict__ z,
        float* __restrict__ xcT, float* __restrict__ zT){
    __shared__ float tile[32][33];
    int which = blockIdx.z >> 1;
    int b = blockIdx.z & 1;
    const float* src = which ? z : xc;
    float* dst = which ? zT : xcT;
    int l0 = blockIdx.x*32, d0 = blockIdx.y*32;
    int tx = threadIdx.x & 31, ty = threadIdx.x >> 5;
    #pragma unroll
    for(int j=0;j<4;j++)
        tile[ty+8*j][tx] = src[((size_t)b*DI + d0+ty+8*j)*LL + l0+tx];
    __syncthreads();
    #pragma unroll
    for(int j=0;j<4;j++)
        dst[((size_t)b*LL + l0+ty+8*j)*DI + d0+tx] = tile[tx][ty+8*j];
}

// ---------- delta precompute: deltaT[bk][p][d] = softplus(dtb + dt_w . dts) ----------
__global__ __launch_bounds__(256) void k_delta(const float* __restrict__ pj, const float* __restrict__ dtw,
        const float* __restrict__ dtb, float* __restrict__ deltaT){
    __shared__ float pjs[RR*32];
    int p0 = blockIdx.x*32;
    int bk = blockIdx.z; int b = bk>>2, k = bk&3;
    int lane = threadIdx.x & 63, sub = threadIdx.x >> 6;
    int d = blockIdx.y*64 + lane;
    const float* pjb = pj + ((size_t)b*(KK*KC) + k*KC)*LL;
    for(int idx=threadIdx.x; idx<RR*32; idx+=256){
        int r = idx>>5, pp = idx&31;
        pjs[idx] = pjb[(size_t)r*LL + p0+pp];
    }
    __syncthreads();
    float wr[RR];
    #pragma unroll
    for(int r=0;r<RR;r++) wr[r] = dtw[((size_t)k*DI + d)*RR + r];
    float dtbv = dtb[k*DI + d];
    #pragma unroll
    for(int i=0;i<8;i++){
        int pp = sub*8+i;
        float acc = dtbv;
        #pragma unroll
        for(int r=0;r<RR;r++) acc += wr[r]*pjs[r*32+pp];
        deltaT[((size_t)bk*LL + p0+pp)*DI + d] = softplus_f(acc);
    }
}

// ---------- chunked selective scan ----------
__device__ __forceinline__ int perm_pos(int k, int l){
    int lk = (k>=2) ? (LL-1-l) : l;
    return (k&1) ? ((lk%WW)*WW + lk/WW) : lk;
}

__global__ __launch_bounds__(384) void k_scan1(const float* __restrict__ xcT, const float* __restrict__ pj,
        const float* __restrict__ deltaT, const float* __restrict__ alogs,
        float* __restrict__ gbuf, float* __restrict__ Sbuf){
    __shared__ float bs[LEN*16];
    int chunk = blockIdx.x;
    int bk = blockIdx.y; int b = bk>>2, k = bk&3;
    int lane = threadIdx.x & 63, wv = threadIdx.x >> 6;
    int d = wv*64 + lane;
    const float* pjb = pj + ((size_t)b*(KK*KC) + k*KC)*LL;
    for(int idx=threadIdx.x; idx<LEN*16; idx+=384){
        int s = idx>>4, n = idx&15;
        int p = perm_pos(k, chunk*LEN+s);
        bs[idx] = pjb[(size_t)(RR+n)*LL + p];
    }
    __syncthreads();
    float a[NN], h[NN];
    #pragma unroll
    for(int n=0;n<NN;n++){ a[n] = -__expf(alogs[((size_t)k*DI + d)*NN + n]); h[n]=0.f; }
    float S = 0.f;
    const float* dptr = deltaT + (size_t)bk*LL*DI + d;
    const float* uptr = xcT + (size_t)b*LL*DI + d;
    for(int s=0;s<LEN;s++){
        int p = perm_pos(k, chunk*LEN+s);
        float dt = dptr[(size_t)p*DI];
        float u  = uptr[(size_t)p*DI];
        S += dt;
        float du = dt*u;
        #pragma unroll
        for(int nq=0;nq<4;nq++){
            float4 Bq = *reinterpret_cast<const float4*>(bs + s*16 + nq*4);
            h[nq*4+0] = __expf(dt*a[nq*4+0])*h[nq*4+0] + du*Bq.x;
            h[nq*4+1] = __expf(dt*a[nq*4+1])*h[nq*4+1] + du*Bq.y;
            h[nq*4+2] = __expf(dt*a[nq*4+2])*h[nq*4+2] + du*Bq.z;
            h[nq*4+3] = __expf(dt*a[nq*4+3])*h[nq*4+3] + du*Bq.w;
        }
    }
    int base = (bk*CH + chunk)*NN;
    #pragma unroll
    for(int n=0;n<NN;n++) gbuf[(size_t)(base+n)*DI + d] = h[n];
    Sbuf[(size_t)(bk*CH + chunk)*DI + d] = S;
}

__global__ __launch_bounds__(256) void k_scan2(const float* __restrict__ alogs, const float* __restrict__ Sbuf,
        float* __restrict__ gbuf){
    int id = blockIdx.x*256 + threadIdx.x;
    int d = id % DI;
    int n = (id/DI) % NN;
    int bk = id/(DI*NN);
    int k = bk & 3;
    float a = -__expf(alogs[((size_t)k*DI + d)*NN + n]);
    float h = 0.f;
    for(int j=0;j<CH;j++){
        float S = Sbuf[(size_t)(bk*CH + j)*DI + d];
        size_t gi = (size_t)((bk*CH + j)*NN + n)*DI + d;
        float g = gbuf[gi];
        gbuf[gi] = h;                 // store h0 for chunk j in place
        h = __expf(a*S)*h + g;
    }
}

// NOTE: yout aliases deltaT (same index, dt read before y write, each addr touched once)
__global__ __launch_bounds__(384) void k_scan3(const float* __restrict__ xcT, const float* __restrict__ pj,
        const float* deltaT, const float* __restrict__ alogs,
        const float* __restrict__ gbuf, float* yout){
    __shared__ float bs[LEN*32];
    int chunk = blockIdx.x;
    int bk = blockIdx.y; int b = bk>>2, k = bk&3;
    int lane = threadIdx.x & 63, wv = threadIdx.x >> 6;
    int d = wv*64 + lane;
    const float* pjb = pj + ((size_t)b*(KK*KC) + k*KC)*LL;
    for(int idx=threadIdx.x; idx<LEN*32; idx+=384){
        int s = idx>>5, c = idx&31;
        int p = perm_pos(k, chunk*LEN+s);
        bs[idx] = pjb[(size_t)(RR+c)*LL + p];
    }
    __syncthreads();
    float a[NN], h[NN];
    int base = (bk*CH + chunk)*NN;
    #pragma unroll
    for(int n=0;n<NN;n++){
        a[n] = -__expf(alogs[((size_t)k*DI + d)*NN + n]);
        h[n] = gbuf[(size_t)(base+n)*DI + d];
    }
    const float* dptr = deltaT + (size_t)bk*LL*DI + d;
    const float* uptr = xcT + (size_t)b*LL*DI + d;
    float* yptr = yout + (size_t)bk*LL*DI + d;
    for(int s=0;s<LEN;s++){
        int p = perm_pos(k, chunk*LEN+s);
        float dt = dptr[(size_t)p*DI];
        float u  = uptr[(size_t)p*DI];
        float du = dt*u;
        float y = 0.f;
        #pragma unroll
        for(int nq=0;nq<4;nq++){
            float4 Bq = *reinterpret_cast<const float4*>(bs + s*32 + nq*4);
            float4 Cq = *reinterpret_cast<const float4*>(bs + s*32 + 16 + nq*4);
            h[nq*4+0] = __expf(dt*a[nq*4+0])*h[nq*4+0] + du*Bq.x;  y += h[nq*4+0]*Cq.x;
            h[nq*4+1] = __expf(dt*a[nq*4+1])*h[nq*4+1] + du*Bq.y;  y += h[nq*4+1]*Cq.y;
            h[nq*4+2] = __expf(dt*a[nq*4+2])*h[nq*4+2] + du*Bq.z;  y += h[nq*4+2]*Cq.z;
            h[nq*4+3] = __expf(dt*a[nq*4+3])*h[nq*4+3] + du*Bq.w;  y += h[nq*4+3]*Cq.w;
        }
        yptr[(size_t)p*DI] = y;
    }
}

// ---------- merge: sum 4 dirs + D-term, LayerNorm, silu(z) gate, transpose to (b,C,L) ----------
__global__ __launch_bounds__(256) void k_merge(const float* __restrict__ yout, const float* __restrict__ xcT,
        const float* __restrict__ zT, const float* __restrict__ Ds,
        const float* __restrict__ lng, const float* __restrict__ lnb,
        float* __restrict__ ygT){
    __shared__ float tile[32*385];
    int p0 = blockIdx.x*32; int b = blockIdx.y;
    for(int idx=threadIdx.x; idx<32*DI; idx+=256){
        int pp = idx/DI, d = idx%DI; int p = p0+pp;
        float dsum = Ds[d] + Ds[DI+d] + Ds[2*DI+d] + Ds[3*DI+d];
        float v = dsum * xcT[((size_t)b*LL + p)*DI + d];
        #pragma unroll
        for(int kk=0;kk<4;kk++) v += yout[((size_t)(b*4+kk)*LL + p)*DI + d];
        tile[pp*385 + d] = v;
    }
    __syncthreads();
    int lane = threadIdx.x & 63, wv = threadIdx.x >> 6;
    for(int i=0;i<8;i++){
        int pp = wv*8 + i; int p = p0+pp;
        float s1=0.f, s2=0.f;
        float vals[6];
        #pragma unroll
        for(int j=0;j<6;j++){ float v = tile[pp*385 + lane + 64*j]; vals[j]=v; s1+=v; s2+=v*v; }
        #pragma unroll
        for(int m=1;m<64;m<<=1){ s1 += __shfl_xor(s1,m); s2 += __shfl_xor(s2,m); }
        float mu = s1*(1.0f/DI);
        float var = s2*(1.0f/DI) - mu*mu;
        float rstd = rsqrtf(var + 1e-5f);
        #pragma unroll
        for(int j=0;j<6;j++){
            int c = lane + 64*j;
            float zv = zT[((size_t)b*LL + p)*DI + c];
            float y = (vals[j]-mu)*rstd*lng[c] + lnb[c];
            tile[pp*385 + c] = y * silu_f(zv);
        }
    }
    __syncthreads();
    for(int idx=threadIdx.x; idx<32*DI; idx+=256){
        int pp = idx & 31, d = idx >> 5;
        ygT[((size_t)b*DI + d)*LL + p0 + pp] = tile[pp*385 + d];
    }
}

__global__ __launch_bounds__(256) void k_outproj(const float* __restrict__ ygT, const float* __restrict__ w,
        float* __restrict__ yo){
    __shared__ float wl[16*DI];
    int l = blockIdx.x*256 + threadIdx.x;
    int o0 = blockIdx.y*16; int b = blockIdx.z;
    float acc[16];
    #pragma unroll
    for(int j=0;j<16;j++) acc[j] = 0.f;
    gemm16_acc<DI>(ygT + (size_t)b*DI*LL + l, w, o0, wl, acc, threadIdx.x);
    float* ob = yo + (size_t)b*DM*LL + o0*LL + l;
    #pragma unroll
    for(int j=0;j<16;j++) ob[j*LL] = acc[j];
}

__global__ __launch_bounds__(256) void k_final(const float* __restrict__ yo, const float* __restrict__ x1,
        const float* __restrict__ w, const float* __restrict__ bias, float* __restrict__ out){
    __shared__ float wl[16*DM];
    int l = blockIdx.x*256 + threadIdx.x;
    int o0 = blockIdx.y*16; int b = blockIdx.z;
    const float* yb = yo + (size_t)b*DM*LL + l;
    const float* rb = x1 + (size_t)b*DM*LL + l;
    float acc[16];
    #pragma unroll
    for(int j=0;j<16;j++) acc[j] = bias[o0+j];
    for(int idx=threadIdx.x; idx<16*DM; idx+=256) wl[idx] = w[(size_t)o0*DM + idx];
    __syncthreads();
    #pragma unroll 2
    for(int c=0;c<DM;c+=4){
        float x0=yb[(size_t)(c+0)*LL]+rb[(size_t)(c+0)*LL];
        float x1v=yb[(size_t)(c+1)*LL]+rb[(size_t)(c+1)*LL];
        float x2=yb[(size_t)(c+2)*LL]+rb[(size_t)(c+2)*LL];
        float x3=yb[(size_t)(c+3)*LL]+rb[(size_t)(c+3)*LL];
        #pragma unroll
        for(int o=0;o<16;o++){
            float4 wq = *reinterpret_cast<const float4*>(wl + o*DM + c);
            acc[o] = fmaf(wq.x,x0, fmaf(wq.y,x1v, fmaf(wq.z,x2, fmaf(wq.w,x3, acc[o]))));
        }
    }
    float* ob = out + (size_t)b*CI*LL + o0*LL + l;
    #pragma unroll
    for(int j=0;j<16;j++) ob[j*LL] = gelu_f(acc[j]);
}

extern "C" void kernel_launch(void* const* d_in, const int* in_sizes, int n_in,
                              void* d_out, int out_size, void* d_ws, size_t ws_size,
                              hipStream_t stream) {
    const float* x        = (const float*)d_in[0];
    const float* w_init   = (const float*)d_in[1];
    const float* b_init   = (const float*)d_in[2];
    const float* w_fina   = (const float*)d_in[3];
    const float* b_fina   = (const float*)d_in[4];
    const float* in_proj_w= (const float*)d_in[5];
    const float* conv_w   = (const float*)d_in[6];
    const float* conv_b   = (const float*)d_in[7];
    const float* x_proj_w = (const float*)d_in[8];
    const float* dt_w     = (const float*)d_in[9];
    const float* dt_b     = (const float*)d_in[10];
    const float* A_logs   = (const float*)d_in[11];
    const float* Ds       = (const float*)d_in[12];
    const float* ln_g     = (const float*)d_in[13];
    const float* ln_b     = (const float*)d_in[14];
    const float* out_proj_w=(const float*)d_in[15];

    float* ws = (float*)d_ws;
    float* x1   = ws;                      // 884736
    float* xx   = x1 + 884736;             // 1769472
    float* z    = xx + 1769472;            // 1769472
    float* xc   = z  + 1769472;            // 1769472
    float* xcT  = xc + 1769472;            // 1769472
    float* zT   = xcT+ 1769472;            // 1769472
    float* pj   = zT + 1769472;            // 811008
    float* deltaT = pj + 811008;           // 7077888  (bk,p,d) — also reused as yout
    // total 17,620,992 floats = 70.5 MB

    // aliases (lifetimes don't overlap):
    float* gbuf = xx;                      // 4718592 (xx+z+xc dead after k_transpose)
    float* Sbuf = xx + 4718592;            // 294912
    float* yout = deltaT;                  // scan3 reads dt then writes y at the same index
    float* ygT  = xx;                      // merge output (gbuf dead after scan3)
    float* yo   = z;                       // outproj output

    dim3 blk(256);
    k_init   <<<dim3(9,12,BB), blk, 0, stream>>>(x, w_init, b_init, x1);
    k_inproj <<<dim3(9,48,BB), blk, 0, stream>>>(x1, in_proj_w, xx, z);
    k_dwconv <<<dim3(9,DI,BB), blk, 0, stream>>>(xx, conv_w, conv_b, xc);
    k_proj   <<<dim3(9,11,BB), blk, 0, stream>>>(xc, x_proj_w, pj);
    k_transpose<<<dim3(72,12,2*BB), blk, 0, stream>>>(xc, z, xcT, zT);
    k_delta  <<<dim3(72,6,BB*KK), blk, 0, stream>>>(pj, dt_w, dt_b, deltaT);
    k_scan1  <<<dim3(CH,BB*KK), dim3(384), 0, stream>>>(xcT, pj, deltaT, A_logs, gbuf, Sbuf);
    k_scan2  <<<dim3(192), blk, 0, stream>>>(A_logs, Sbuf, gbuf);
    k_scan3  <<<dim3(CH,BB*KK), dim3(384), 0, stream>>>(xcT, pj, deltaT, A_logs, gbuf, yout);
    k_merge  <<<dim3(72,BB), blk, 0, stream>>>(yout, xcT, zT, Ds, ln_g, ln_b, ygT);
    k_outproj<<<dim3(9,12,BB), blk, 0, stream>>>(ygT, out_proj_w, yo);
    k_final  <<<dim3(9,6,BB), blk, 0, stream>>>(yo, x1, w_fina, b_fina, (float*)d_out);
}

// Round 3
// 360.746 us; speedup vs baseline: 1.9467x; 1.4265x over previous
//
#include <hip/hip_runtime.h>
#include <math.h>

#define LL 2304
#define HH 48
#define WW 48
#define BB 2
#define CI 96
#define DM 192
#define DI 384
#define KK 4
#define RR 12
#define NN 16
#define KC 44
#define CH 96
#define LEN 24   // CH*LEN == LL

__device__ __forceinline__ float gelu_f(float x){
    return 0.5f*x*(1.0f+erff(x*0.70710678118654752f));
}
__device__ __forceinline__ float silu_f(float x){
    return x/(1.0f+__expf(-x));
}
__device__ __forceinline__ float softplus_f(float x){
    return fmaxf(x,0.0f) + log1pf(__expf(-fabsf(x)));
}

// ---------- GEMM pattern: 256 l-lanes x OT outputs, weights staged in LDS ----------
template<int C, int OT>
__device__ __forceinline__ void gemmN_acc(const float* __restrict__ xb, const float* __restrict__ w,
        int o0, float* wl, float acc[OT], int tid){
    for(int idx=tid; idx<OT*C; idx+=256) wl[idx] = w[(size_t)o0*C + idx];
    __syncthreads();
    #pragma unroll 2
    for(int c=0;c<C;c+=4){
        float x0=xb[(size_t)(c+0)*LL], x1=xb[(size_t)(c+1)*LL];
        float x2=xb[(size_t)(c+2)*LL], x3=xb[(size_t)(c+3)*LL];
        #pragma unroll
        for(int o=0;o<OT;o++){
            float4 wq = *reinterpret_cast<const float4*>(wl + o*C + c);
            acc[o] = fmaf(wq.x,x0, fmaf(wq.y,x1, fmaf(wq.z,x2, fmaf(wq.w,x3, acc[o]))));
        }
    }
}

__global__ __launch_bounds__(256) void k_init(const float* __restrict__ x, const float* __restrict__ w,
        const float* __restrict__ bias, float* __restrict__ x1){
    __shared__ float wl[8*CI];
    int l = blockIdx.x*256 + threadIdx.x;
    int o0 = blockIdx.y*8; int b = blockIdx.z;
    float acc[8];
    #pragma unroll
    for(int j=0;j<8;j++) acc[j] = bias[o0+j];
    gemmN_acc<CI,8>(x + (size_t)b*CI*LL + l, w, o0, wl, acc, threadIdx.x);
    float* ob = x1 + (size_t)b*DM*LL + o0*LL + l;
    #pragma unroll
    for(int j=0;j<8;j++) ob[j*LL] = gelu_f(acc[j]);
}

__global__ __launch_bounds__(256) void k_inproj(const float* __restrict__ x1, const float* __restrict__ w,
        float* __restrict__ xx, float* __restrict__ z){
    __shared__ float wl[16*DM];
    int l = blockIdx.x*256 + threadIdx.x;
    int o0 = blockIdx.y*16; int b = blockIdx.z;
    float acc[16];
    #pragma unroll
    for(int j=0;j<16;j++) acc[j] = 0.f;
    gemmN_acc<DM,16>(x1 + (size_t)b*DM*LL + l, w, o0, wl, acc, threadIdx.x);
    float* ob = (o0 < DI) ? (xx + (size_t)b*DI*LL + o0*LL + l)
                          : (z  + (size_t)b*DI*LL + (o0-DI)*LL + l);
    #pragma unroll
    for(int j=0;j<16;j++) ob[j*LL] = acc[j];
}

__global__ __launch_bounds__(256) void k_dwconv(const float* __restrict__ xx, const float* __restrict__ cw,
        const float* __restrict__ cb, float* __restrict__ xc){
    int l = blockIdx.x*256 + threadIdx.x;
    int d = blockIdx.y; int b = blockIdx.z;
    int h = l/WW, w = l%WW;
    const float* src = xx + ((size_t)b*DI + d)*LL;
    float acc = cb[d];
    #pragma unroll
    for(int dh=-1;dh<=1;dh++){
        int hh = h+dh; if(hh<0||hh>=HH) continue;
        #pragma unroll
        for(int dw=-1;dw<=1;dw++){
            int w2 = w+dw; if(w2<0||w2>=WW) continue;
            acc += cw[d*9 + (dh+1)*3 + (dw+1)] * src[hh*WW + w2];
        }
    }
    xc[((size_t)b*DI + d)*LL + l] = silu_f(acc);
}

__global__ __launch_bounds__(256) void k_proj(const float* __restrict__ xc, const float* __restrict__ w,
        float* __restrict__ pj){
    __shared__ float wl[8*DI];
    int l = blockIdx.x*256 + threadIdx.x;
    int o0 = blockIdx.y*8; int b = blockIdx.z;
    float acc[8];
    #pragma unroll
    for(int j=0;j<8;j++) acc[j] = 0.f;
    gemmN_acc<DI,8>(xc + (size_t)b*DI*LL + l, w, o0, wl, acc, threadIdx.x);
    float* ob = pj + ((size_t)b*(KK*KC) + o0)*LL + l;
    #pragma unroll
    for(int j=0;j<8;j++) ob[j*LL] = acc[j];
}

// ---------- transpose (b,C,L) -> (b,L,C) for xc and z ----------
__global__ __launch_bounds__(256) void k_transpose(const float* __restrict__ xc, const float* __restrict__ z,
        float* __restrict__ xcT, float* __restrict__ zT){
    __shared__ float tile[32][33];
    int which = blockIdx.z >> 1;
    int b = blockIdx.z & 1;
    const float* src = which ? z : xc;
    float* dst = which ? zT : xcT;
    int l0 = blockIdx.x*32, d0 = blockIdx.y*32;
    int tx = threadIdx.x & 31, ty = threadIdx.x >> 5;
    #pragma unroll
    for(int j=0;j<4;j++)
        tile[ty+8*j][tx] = src[((size_t)b*DI + d0+ty+8*j)*LL + l0+tx];
    __syncthreads();
    #pragma unroll
    for(int j=0;j<4;j++)
        dst[((size_t)b*LL + l0+ty+8*j)*DI + d0+tx] = tile[tx][ty+8*j];
}

// ---------- delta precompute: deltaT[bk][p][d] = softplus(dtb + dt_w . dts) ----------
__global__ __launch_bounds__(256) void k_delta(const float* __restrict__ pj, const float* __restrict__ dtw,
        const float* __restrict__ dtb, float* __restrict__ deltaT){
    __shared__ float pjs[RR*32];
    int p0 = blockIdx.x*32;
    int bk = blockIdx.z; int b = bk>>2, k = bk&3;
    int lane = threadIdx.x & 63, sub = threadIdx.x >> 6;
    int d = blockIdx.y*64 + lane;
    const float* pjb = pj + ((size_t)b*(KK*KC) + k*KC)*LL;
    for(int idx=threadIdx.x; idx<RR*32; idx+=256){
        int r = idx>>5, pp = idx&31;
        pjs[idx] = pjb[(size_t)r*LL + p0+pp];
    }
    __syncthreads();
    float wr[RR];
    #pragma unroll
    for(int r=0;r<RR;r++) wr[r] = dtw[((size_t)k*DI + d)*RR + r];
    float dtbv = dtb[k*DI + d];
    #pragma unroll
    for(int i=0;i<8;i++){
        int pp = sub*8+i;
        float acc = dtbv;
        #pragma unroll
        for(int r=0;r<RR;r++) acc += wr[r]*pjs[r*32+pp];
        deltaT[((size_t)bk*LL + p0+pp)*DI + d] = softplus_f(acc);
    }
}

// ---------- chunked selective scan ----------
__device__ __forceinline__ int perm_pos(int k, int l){
    int lk = (k>=2) ? (LL-1-l) : l;
    return (k&1) ? ((lk%WW)*WW + lk/WW) : lk;
}

__global__ __launch_bounds__(384) void k_scan1(const float* __restrict__ xcT, const float* __restrict__ pj,
        const float* __restrict__ deltaT, const float* __restrict__ alogs,
        float* __restrict__ gbuf, float* __restrict__ Sbuf){
    __shared__ float bs[LEN*16];
    int chunk = blockIdx.x;
    int bk = blockIdx.y; int b = bk>>2, k = bk&3;
    int lane = threadIdx.x & 63, wv = threadIdx.x >> 6;
    int d = wv*64 + lane;
    const float* pjb = pj + ((size_t)b*(KK*KC) + k*KC)*LL;
    for(int idx=threadIdx.x; idx<LEN*16; idx+=384){
        int s = idx>>4, n = idx&15;
        int p = perm_pos(k, chunk*LEN+s);
        bs[idx] = pjb[(size_t)(RR+n)*LL + p];
    }
    __syncthreads();
    float a[NN], h[NN];
    #pragma unroll
    for(int n=0;n<NN;n++){ a[n] = -__expf(alogs[((size_t)k*DI + d)*NN + n]); h[n]=0.f; }
    float S = 0.f;
    const float* dptr = deltaT + (size_t)bk*LL*DI + d;
    const float* uptr = xcT + (size_t)b*LL*DI + d;
    for(int s=0;s<LEN;s++){
        int p = perm_pos(k, chunk*LEN+s);
        float dt = dptr[(size_t)p*DI];
        float u  = uptr[(size_t)p*DI];
        S += dt;
        float du = dt*u;
        #pragma unroll
        for(int nq=0;nq<4;nq++){
            float4 Bq = *reinterpret_cast<const float4*>(bs + s*16 + nq*4);
            h[nq*4+0] = __expf(dt*a[nq*4+0])*h[nq*4+0] + du*Bq.x;
            h[nq*4+1] = __expf(dt*a[nq*4+1])*h[nq*4+1] + du*Bq.y;
            h[nq*4+2] = __expf(dt*a[nq*4+2])*h[nq*4+2] + du*Bq.z;
            h[nq*4+3] = __expf(dt*a[nq*4+3])*h[nq*4+3] + du*Bq.w;
        }
    }
    int base = (bk*CH + chunk)*NN;
    #pragma unroll
    for(int n=0;n<NN;n++) gbuf[(size_t)(base+n)*DI + d] = h[n];
    Sbuf[(size_t)(bk*CH + chunk)*DI + d] = S;
}

__global__ __launch_bounds__(256) void k_scan2(const float* __restrict__ alogs, const float* __restrict__ Sbuf,
        float* __restrict__ gbuf){
    int id = blockIdx.x*256 + threadIdx.x;
    int d = id % DI;
    int n = (id/DI) % NN;
    int bk = id/(DI*NN);
    int k = bk & 3;
    float a = -__expf(alogs[((size_t)k*DI + d)*NN + n]);
    float h = 0.f;
    for(int j=0;j<CH;j++){
        float S = Sbuf[(size_t)(bk*CH + j)*DI + d];
        size_t gi = (size_t)((bk*CH + j)*NN + n)*DI + d;
        float g = gbuf[gi];
        gbuf[gi] = h;                 // store h0 for chunk j in place
        h = __expf(a*S)*h + g;
    }
}

// NOTE: yout aliases deltaT (same index, dt read before y write, each addr touched once)
__global__ __launch_bounds__(384) void k_scan3(const float* __restrict__ xcT, const float* __restrict__ pj,
        const float* deltaT, const float* __restrict__ alogs,
        const float* __restrict__ gbuf, float* yout){
    __shared__ float bs[LEN*32];
    int chunk = blockIdx.x;
    int bk = blockIdx.y; int b = bk>>2, k = bk&3;
    int lane = threadIdx.x & 63, wv = threadIdx.x >> 6;
    int d = wv*64 + lane;
    const float* pjb = pj + ((size_t)b*(KK*KC) + k*KC)*LL;
    for(int idx=threadIdx.x; idx<LEN*32; idx+=384){
        int s = idx>>5, c = idx&31;
        int p = perm_pos(k, chunk*LEN+s);
        bs[idx] = pjb[(size_t)(RR+c)*LL + p];
    }
    __syncthreads();
    float a[NN], h[NN];
    int base = (bk*CH + chunk)*NN;
    #pragma unroll
    for(int n=0;n<NN;n++){
        a[n] = -__expf(alogs[((size_t)k*DI + d)*NN + n]);
        h[n] = gbuf[(size_t)(base+n)*DI + d];
    }
    const float* dptr = deltaT + (size_t)bk*LL*DI + d;
    const float* uptr = xcT + (size_t)b*LL*DI + d;
    float* yptr = yout + (size_t)bk*LL*DI + d;
    for(int s=0;s<LEN;s++){
        int p = perm_pos(k, chunk*LEN+s);
        float dt = dptr[(size_t)p*DI];
        float u  = uptr[(size_t)p*DI];
        float du = dt*u;
        float y = 0.f;
        #pragma unroll
        for(int nq=0;nq<4;nq++){
            float4 Bq = *reinterpret_cast<const float4*>(bs + s*32 + nq*4);
            float4 Cq = *reinterpret_cast<const float4*>(bs + s*32 + 16 + nq*4);
            h[nq*4+0] = __expf(dt*a[nq*4+0])*h[nq*4+0] + du*Bq.x;  y += h[nq*4+0]*Cq.x;
            h[nq*4+1] = __expf(dt*a[nq*4+1])*h[nq*4+1] + du*Bq.y;  y += h[nq*4+1]*Cq.y;
            h[nq*4+2] = __expf(dt*a[nq*4+2])*h[nq*4+2] + du*Bq.z;  y += h[nq*4+2]*Cq.z;
            h[nq*4+3] = __expf(dt*a[nq*4+3])*h[nq*4+3] + du*Bq.w;  y += h[nq*4+3]*Cq.w;
        }
        yptr[(size_t)p*DI] = y;
    }
}

// ---------- merge: sum 4 dirs + D-term, LayerNorm, silu(z) gate, transpose to (b,C,L) ----------
__global__ __launch_bounds__(256) void k_merge(const float* __restrict__ yout, const float* __restrict__ xcT,
        const float* __restrict__ zT, const float* __restrict__ Ds,
        const float* __restrict__ lng, const float* __restrict__ lnb,
        float* __restrict__ ygT){
    __shared__ float tile[32*385];
    int p0 = blockIdx.x*32; int b = blockIdx.y;
    for(int idx=threadIdx.x; idx<32*DI; idx+=256){
        int pp = idx/DI, d = idx%DI; int p = p0+pp;
        float dsum = Ds[d] + Ds[DI+d] + Ds[2*DI+d] + Ds[3*DI+d];
        float v = dsum * xcT[((size_t)b*LL + p)*DI + d];
        #pragma unroll
        for(int kk=0;kk<4;kk++) v += yout[((size_t)(b*4+kk)*LL + p)*DI + d];
        tile[pp*385 + d] = v;
    }
    __syncthreads();
    int lane = threadIdx.x & 63, wv = threadIdx.x >> 6;
    for(int i=0;i<8;i++){
        int pp = wv*8 + i; int p = p0+pp;
        float s1=0.f, s2=0.f;
        float vals[6];
        #pragma unroll
        for(int j=0;j<6;j++){ float v = tile[pp*385 + lane + 64*j]; vals[j]=v; s1+=v; s2+=v*v; }
        #pragma unroll
        for(int m=1;m<64;m<<=1){ s1 += __shfl_xor(s1,m); s2 += __shfl_xor(s2,m); }
        float mu = s1*(1.0f/DI);
        float var = s2*(1.0f/DI) - mu*mu;
        float rstd = rsqrtf(var + 1e-5f);
        #pragma unroll
        for(int j=0;j<6;j++){
            int c = lane + 64*j;
            float zv = zT[((size_t)b*LL + p)*DI + c];
            float y = (vals[j]-mu)*rstd*lng[c] + lnb[c];
            tile[pp*385 + c] = y * silu_f(zv);
        }
    }
    __syncthreads();
    for(int idx=threadIdx.x; idx<32*DI; idx+=256){
        int pp = idx & 31, d = idx >> 5;
        ygT[((size_t)b*DI + d)*LL + p0 + pp] = tile[pp*385 + d];
    }
}

// out-proj with fused residual: yo = W_o . ygT + x1
__global__ __launch_bounds__(256) void k_outproj(const float* __restrict__ ygT, const float* __restrict__ w,
        const float* __restrict__ x1, float* __restrict__ yo){
    __shared__ float wl[8*DI];
    int l = blockIdx.x*256 + threadIdx.x;
    int o0 = blockIdx.y*8; int b = blockIdx.z;
    float acc[8];
    #pragma unroll
    for(int j=0;j<8;j++) acc[j] = 0.f;
    gemmN_acc<DI,8>(ygT + (size_t)b*DI*LL + l, w, o0, wl, acc, threadIdx.x);
    const float* rb = x1 + (size_t)b*DM*LL + o0*LL + l;
    float* ob = yo + (size_t)b*DM*LL + o0*LL + l;
    #pragma unroll
    for(int j=0;j<8;j++) ob[j*LL] = acc[j] + rb[j*LL];
}

__global__ __launch_bounds__(256) void k_final(const float* __restrict__ yo,
        const float* __restrict__ w, const float* __restrict__ bias, float* __restrict__ out){
    __shared__ float wl[4*DM];
    int l = blockIdx.x*256 + threadIdx.x;
    int o0 = blockIdx.y*4; int b = blockIdx.z;
    float acc[4];
    #pragma unroll
    for(int j=0;j<4;j++) acc[j] = bias[o0+j];
    gemmN_acc<DM,4>(yo + (size_t)b*DM*LL + l, w, o0, wl, acc, threadIdx.x);
    float* ob = out + (size_t)b*CI*LL + o0*LL + l;
    #pragma unroll
    for(int j=0;j<4;j++) ob[j*LL] = gelu_f(acc[j]);
}

extern "C" void kernel_launch(void* const* d_in, const int* in_sizes, int n_in,
                              void* d_out, int out_size, void* d_ws, size_t ws_size,
                              hipStream_t stream) {
    const float* x        = (const float*)d_in[0];
    const float* w_init   = (const float*)d_in[1];
    const float* b_init   = (const float*)d_in[2];
    const float* w_fina   = (const float*)d_in[3];
    const float* b_fina   = (const float*)d_in[4];
    const float* in_proj_w= (const float*)d_in[5];
    const float* conv_w   = (const float*)d_in[6];
    const float* conv_b   = (const float*)d_in[7];
    const float* x_proj_w = (const float*)d_in[8];
    const float* dt_w     = (const float*)d_in[9];
    const float* dt_b     = (const float*)d_in[10];
    const float* A_logs   = (const float*)d_in[11];
    const float* Ds       = (const float*)d_in[12];
    const float* ln_g     = (const float*)d_in[13];
    const float* ln_b     = (const float*)d_in[14];
    const float* out_proj_w=(const float*)d_in[15];

    float* ws = (float*)d_ws;
    float* x1   = ws;                      // 884736
    float* xx   = x1 + 884736;             // 1769472
    float* z    = xx + 1769472;            // 1769472
    float* xc   = z  + 1769472;            // 1769472
    float* xcT  = xc + 1769472;            // 1769472
    float* zT   = xcT+ 1769472;            // 1769472
    float* pj   = zT + 1769472;            // 811008
    float* deltaT = pj + 811008;           // 7077888  (bk,p,d) — also reused as yout
    // total 17,620,992 floats = 70.5 MB

    // aliases (lifetimes don't overlap):
    float* gbuf = xx;                      // 4718592 (xx+z+xc dead after k_transpose)
    float* Sbuf = xx + 4718592;            // 294912
    float* yout = deltaT;                  // scan3 reads dt then writes y at the same index
    float* ygT  = xx;                      // merge output (gbuf dead after scan3)
    float* yo   = z;                       // outproj output

    dim3 blk(256);
    k_init   <<<dim3(9,24,BB), blk, 0, stream>>>(x, w_init, b_init, x1);
    k_inproj <<<dim3(9,48,BB), blk, 0, stream>>>(x1, in_proj_w, xx, z);
    k_dwconv <<<dim3(9,DI,BB), blk, 0, stream>>>(xx, conv_w, conv_b, xc);
    k_proj   <<<dim3(9,22,BB), blk, 0, stream>>>(xc, x_proj_w, pj);
    k_transpose<<<dim3(72,12,2*BB), blk, 0, stream>>>(xc, z, xcT, zT);
    k_delta  <<<dim3(72,6,BB*KK), blk, 0, stream>>>(pj, dt_w, dt_b, deltaT);
    k_scan1  <<<dim3(CH,BB*KK), dim3(384), 0, stream>>>(xcT, pj, deltaT, A_logs, gbuf, Sbuf);
    k_scan2  <<<dim3(192), blk, 0, stream>>>(A_logs, Sbuf, gbuf);
    k_scan3  <<<dim3(CH,BB*KK), dim3(384), 0, stream>>>(xcT, pj, deltaT, A_logs, gbuf, yout);
    k_merge  <<<dim3(72,BB), blk, 0, stream>>>(yout, xcT, zT, Ds, ln_g, ln_b, ygT);
    k_outproj<<<dim3(9,24,BB), blk, 0, stream>>>(ygT, out_proj_w, x1, yo);
    k_final  <<<dim3(9,24,BB), blk, 0, stream>>>(yo, w_fina, b_fina, (float*)d_out);
}